// Round 6
// baseline (209.539 us; speedup 1.0000x reference)
//
#include <hip/hip_runtime.h>
#include <math.h>

#define NBINS 36
#define PSTRIDE 44        // patch row stride in LDS words
#define HREP 16           // one histogram replica per 16 lanes
#define HSTRIDE 40        // 38 slots used (36 bins + 2 alias), stride 40

typedef float f32x2 __attribute__((ext_vector_type(2)));

// ---- one-block setup: gaussian weight table (pre-scaled) + smooth kernel, parallel ----
__global__ __launch_bounds__(64) void setup_tables(double* __restrict__ smkws,
                                                   float* __restrict__ gws) {
    const int t = threadIdx.x;
    if (t < 32) {
        double x = (double)t - 15.5;
        double e = exp(-x * x / 56.888888888888886);     // 2*sigma^2, sigma=32/6
        double s = e;
        #pragma unroll
        for (int o = 16; o >= 1; o >>= 1) s += __shfl_xor(s, o);
        // scale = 2^15 / sqrt(8): bakes the /8 Sobel norm and 2^30 fixed-point into w=gy*gx
        gws[t] = (float)((e / s) * 11585.237502960395);
    }
    if (t < 3) {   // thread n computes Bessel I_n(t=2.56) via the reference's series
        const double tt = 2.56;
        double q = tt * tt * 0.25;
        double term = 1.0;
        for (int i = 1; i <= t; ++i) term *= (tt * 0.5) / (double)i;
        double acc = term;
        for (int k = 1; k <= 40; ++k) { term *= q / ((double)k * (double)(k + t)); acc += term; }
        double I0 = __shfl(acc, 0), I1 = __shfl(acc, 1), I2 = __shfl(acc, 2);
        double S  = I0 + 2.0 * (I1 + I2);                // exp(-t) cancels
        smkws[t] = acc / S;                              // [0]=center,[1]=mid,[2]=outer
    }
}

__launch_bounds__(256)
__global__ void patch_orient_kernel(const float* __restrict__ in, float* __restrict__ out,
                                    const double* __restrict__ smkws,
                                    const float* __restrict__ gws) {
    __shared__ __align__(16) float p[32 * PSTRIDE];
    __shared__ unsigned hist[HREP * HSTRIDE];
    __shared__ __align__(16) float gtab[32];
    __shared__ double binsd[NBINS];
    __shared__ double smv[NBINS];

    const int tid = threadIdx.x;
    const int bid = blockIdx.x;

    // ---- stage patch (coalesced float4), zero histograms, load weight table ----
    {
        const float4 v = reinterpret_cast<const float4*>(in + (size_t)bid * 1024)[tid];
        const int row = tid >> 3, col = (tid & 7) << 2;
        *reinterpret_cast<float4*>(&p[row * PSTRIDE + col]) = v;
    }
    if (tid < 32) gtab[tid] = gws[tid];
    hist[tid] = 0u;
    hist[tid + 256] = 0u;
    if (tid < HREP * HSTRIDE - 512) hist[tid + 512] = 0u;
    __syncthreads();

    // ---- per-thread: 4 consecutive pixels in one row; separable Sobel (unnormalized) ----
    const int y  = tid >> 3;
    const int x0 = (tid & 7) << 2;
    const float* A  = &p[((y == 0)  ? 0  : y - 1) * PSTRIDE];
    const float* Bv = &p[y * PSTRIDE];
    const float* C  = &p[((y == 31) ? 31 : y + 1) * PSTRIDE];
    const int xl = (x0 == 0)  ? 0  : x0 - 1;
    const int xr = (x0 == 28) ? 31 : x0 + 4;

    float s[6], d[6];
    {
        float4 a4 = *reinterpret_cast<const float4*>(A + x0);
        float4 b4 = *reinterpret_cast<const float4*>(Bv + x0);
        float4 c4 = *reinterpret_cast<const float4*>(C + x0);
        float al = A[xl], bl = Bv[xl], cl = C[xl];
        float ar = A[xr], br = Bv[xr], cr = C[xr];
        s[0] = fmaf(2.f, bl,   al)   + cl;   d[0] = cl   - al;
        s[1] = fmaf(2.f, b4.x, a4.x) + c4.x; d[1] = c4.x - a4.x;
        s[2] = fmaf(2.f, b4.y, a4.y) + c4.y; d[2] = c4.y - a4.y;
        s[3] = fmaf(2.f, b4.z, a4.z) + c4.z; d[3] = c4.z - a4.z;
        s[4] = fmaf(2.f, b4.w, a4.w) + c4.w; d[4] = c4.w - a4.w;
        s[5] = fmaf(2.f, br,   ar)   + cr;   d[5] = cr   - ar;
    }

    unsigned* h = &hist[(tid >> 4) * HSTRIDE];   // per-16-lane replica
    const float gwy = gtab[y];
    const float4 gx4 = *reinterpret_cast<const float4*>(&gtab[x0]);
    const f32x2 wP[2] = { gwy * (f32x2){gx4.x, gx4.y},       // g_y*g_x * 2^30/8, pixel pairs
                          gwy * (f32x2){gx4.z, gx4.w} };

    #pragma unroll
    for (int pp = 0; pp < 2; ++pp) {
        const int i0 = pp << 1;
        // pair {px i0, px i0+1}: packed f32 math (v_pk_fma_f32 et al.)
        f32x2 gx8 = { s[i0 + 2] - s[i0],     s[i0 + 3] - s[i0 + 1] };              // 8*gx
        f32x2 gy8 = { fmaf(2.f, d[i0 + 1], d[i0])     + d[i0 + 2],
                      fmaf(2.f, d[i0 + 2], d[i0 + 1]) + d[i0 + 3] };               // 8*gy
        f32x2 m2  = gx8 * gx8 + (gy8 * gy8 + 6.4e-7f);       // 64*(gx^2+gy^2+1e-8), pk fma
        f32x2 rq  = { __builtin_amdgcn_rsqf(m2.x), __builtin_amdgcn_rsqf(m2.y) };
        f32x2 mag = m2 * rq * wP[pp];                        // ref_mag * 2^30
        f32x2 xx  = gx8 + 8e-8f;                             // 8*(gx+1e-8): same sign/ratio
        // scalar per-lane: abs/min/max/rcp (no packed form exists)
        float ax0 = fabsf(xx.x), ay0 = fabsf(gy8.x);
        float ax1 = fabsf(xx.y), ay1 = fabsf(gy8.y);
        f32x2 lo = { fminf(ax0, ay0), fminf(ax1, ay1) };
        f32x2 rc = { __builtin_amdgcn_rcpf(fmaxf(fmaxf(ax0, ay0), 1e-37f)),
                     __builtin_amdgcn_rcpf(fmaxf(fmaxf(ax1, ay1), 1e-37f)) };
        f32x2 t  = lo * rc;                                  // [0,1]
        f32x2 z  = t * t;
        // deg-15 odd minimax of atan on [0,1], coeffs pre-scaled to BIN units (*36/2pi)
        f32x2 pz = (f32x2)(-2.32279295e-2f);
        pz = pz * z + 1.25257116e-1f;
        pz = pz * z + (-3.20340049e-1f);
        pz = pz * z + 5.52446198e-1f;
        pz = pz * z + (-7.96900272e-1f);
        pz = pz * z + 1.14285232f;
        pz = pz * z + (-1.90966007f);
        pz = pz * z + 5.72957413f;
        f32x2 th = t * pz;                                   // atan(lo/hi) in bins [0,4.5]

        #pragma unroll
        for (int j = 0; j < 2; ++j) {
            float T   = j ? th.y  : th.x;
            float axj = j ? ax1   : ax0;
            float ayj = j ? ay1   : ay0;
            float xxj = j ? xx.y  : xx.x;
            float gyj = j ? gy8.y : gy8.x;
            float mg  = j ? mag.y : mag.x;
            T = (ayj > axj)  ? ( 9.f - T) : T;
            T = (xxj < 0.f)  ? (18.f - T) : T;
            T = (gyj < 0.f)  ? -T : T;                       // [-18,18]
            float ob  = T + 18.f;                            // [0,36]
            int   ib  = (int)ob;                             // trunc==floor; [0,36]
            float wo1 = ob - (float)ib;
            float w1  = wo1 * mg;
            float w0  = mg - w1;
            // bins 36,37 alias 0,1 — folded at reduce time (no per-pixel wrap)
            atomicAdd(&h[ib],     (unsigned)w0);
            atomicAdd(&h[ib + 1], (unsigned)w1);
        }
    }
    __syncthreads();

    // ---- wave 0 only: fold aliases, exact u32 sums -> f64 (deterministic) ----
    if (tid < NBINS) {
        unsigned acc = 0;
        #pragma unroll
        for (int r = 0; r < HREP; ++r) acc += hist[r * HSTRIDE + tid];
        if (tid < 2) {
            #pragma unroll
            for (int r = 0; r < HREP; ++r) acc += hist[r * HSTRIDE + NBINS + tid];
        }
        binsd[tid] = (double)acc;
    }
    if (tid < NBINS) {
        double k0 = smkws[0], k1 = smkws[1], k2 = smkws[2];   // center, mid, outer
        int tm2 = tid - 2; if (tm2 < 0) tm2 += 36;
        int tm1 = tid - 1; if (tm1 < 0) tm1 += 36;
        int tp1 = tid + 1; if (tp1 >= 36) tp1 -= 36;
        int tp2 = tid + 2; if (tp2 >= 36) tp2 -= 36;
        smv[tid] = k2 * binsd[tm2] + k1 * binsd[tm1] + k0 * binsd[tid]
                 + k1 * binsd[tp1] + k2 * binsd[tp2];
    }
    if (tid < 64) {
        double v  = (tid < NBINS) ? smv[tid] : -1.0e300;
        int   idx = tid;
        #pragma unroll
        for (int o = 32; o >= 1; o >>= 1) {
            double ov = __shfl_xor(v, o);
            int    oi = __shfl_xor(idx, o);
            if (ov > v || (ov == v && oi < idx)) { v = ov; idx = oi; }
        }
        if (tid == 0) {
            int il = idx - 1; if (il < 0) il += 36;
            int ir = idx + 1; if (ir >= 36) ir -= 36;
            double l = smv[il], r = smv[ir];
            double c = 0.5 * (l - r) / (l + r - 2.0 * v);
            double ang = -(6.283185307179586 * ((double)idx + c) / 36.0 - 3.141592653589793);
            out[bid] = (float)ang;
        }
    }
}

extern "C" void kernel_launch(void* const* d_in, const int* in_sizes, int n_in,
                              void* d_out, int out_size, void* d_ws, size_t ws_size,
                              hipStream_t stream) {
    const float* patch = (const float*)d_in[0];
    float* out = (float*)d_out;
    double* smkws = (double*)d_ws;                       // 3 doubles @ 0
    float*  gws   = (float*)((char*)d_ws + 32);          // 32 floats @ 32
    const int B = in_sizes[0] >> 10;                     // 32768 patches
    setup_tables<<<1, 64, 0, stream>>>(smkws, gws);
    patch_orient_kernel<<<B, 256, 0, stream>>>(patch, out, smkws, gws);
}

// Round 7
// 201.977 us; speedup vs baseline: 1.0374x; 1.0374x over previous
//
#include <hip/hip_runtime.h>
#include <math.h>

#define NBINS 36
#define PSTRIDE 44        // patch row stride in LDS words
#define HREP 16           // one histogram replica per 16 lanes
#define HSTRIDE 40        // 38 slots used (36 bins + 2 alias), stride 40

typedef float f32x2 __attribute__((ext_vector_type(2)));

// ================= compile-time f64 tables (mirror numpy's host math) =================
constexpr double cexp(double a) {            // e^a, a in [-4.3, 0]; ~1e-13 rel err
    double s = 1.0, term = 1.0;
    for (int k = 1; k <= 34; ++k) { term *= a / (double)k; s += term; }
    return s;
}
struct alignas(16) GTab { float g[32]; };
constexpr GTab make_gtab() {
    GTab r{};
    double e[32] = {};
    double sum = 0.0;
    for (int i = 0; i < 32; ++i) {
        double x = (double)i - 15.5;
        e[i] = cexp(-x * x / 56.888888888888886);   // 2*sigma^2, sigma=32/6
        sum += e[i];
    }
    // scale 2^15/sqrt(8): bakes Sobel /8 norm and 2^30 fixed-point into w = gy*gx
    for (int i = 0; i < 32; ++i) r.g[i] = (float)(e[i] / sum * 11585.237502960395);
    return r;
}
constexpr double bessel_iv_c(int n, double t) {      // reference's iv() series
    double q = t * t * 0.25;
    double term = 1.0;
    for (int i = 1; i <= n; ++i) term *= (t * 0.5) / (double)i;
    double s = term;
    for (int k = 1; k <= 40; ++k) { term *= q / ((double)k * (double)(k + n)); s += term; }
    return s;
}
constexpr double BI0 = bessel_iv_c(0, 2.56), BI1 = bessel_iv_c(1, 2.56), BI2 = bessel_iv_c(2, 2.56);
constexpr double BSUM = BI0 + 2.0 * (BI1 + BI2);     // exp(-t) cancels
constexpr double K0 = BI0 / BSUM, K1 = BI1 / BSUM, K2 = BI2 / BSUM;
__device__ __constant__ GTab GW = make_gtab();

// ================= forced packed-f32 ops (VOP3P) =================
__device__ __forceinline__ f32x2 pk_fma(f32x2 a, f32x2 b, f32x2 c) {
    f32x2 d;
    asm("v_pk_fma_f32 %0, %1, %2, %3" : "=v"(d) : "v"(a), "v"(b), "v"(c));
    return d;
}
__device__ __forceinline__ f32x2 pk_mul(f32x2 a, f32x2 b) {
    f32x2 d;
    asm("v_pk_mul_f32 %0, %1, %2" : "=v"(d) : "v"(a), "v"(b));
    return d;
}
#define CP(x) ((f32x2){(x), (x)})

__launch_bounds__(256)
__global__ void patch_orient_kernel(const float* __restrict__ in, float* __restrict__ out) {
    __shared__ __align__(16) float p[32 * PSTRIDE];
    __shared__ unsigned hist[HREP * HSTRIDE];
    __shared__ double binsd[NBINS];
    __shared__ double smv[NBINS];

    const int tid = threadIdx.x;
    const int bid = blockIdx.x;

    // ---- stage patch (coalesced float4), zero histograms ----
    {
        const float4 v = reinterpret_cast<const float4*>(in + (size_t)bid * 1024)[tid];
        const int row = tid >> 3, col = (tid & 7) << 2;
        *reinterpret_cast<float4*>(&p[row * PSTRIDE + col]) = v;
    }
    hist[tid] = 0u;
    hist[tid + 256] = 0u;
    if (tid < HREP * HSTRIDE - 512) hist[tid + 512] = 0u;
    __syncthreads();

    // ---- per-thread: 4 consecutive pixels in one row; separable Sobel (unnormalized) ----
    const int y  = tid >> 3;
    const int x0 = (tid & 7) << 2;
    const float* A  = &p[((y == 0)  ? 0  : y - 1) * PSTRIDE];
    const float* Bv = &p[y * PSTRIDE];
    const float* C  = &p[((y == 31) ? 31 : y + 1) * PSTRIDE];
    const int xl = (x0 == 0)  ? 0  : x0 - 1;
    const int xr = (x0 == 28) ? 31 : x0 + 4;

    float s[6], d[6];
    {
        float4 a4 = *reinterpret_cast<const float4*>(A + x0);
        float4 b4 = *reinterpret_cast<const float4*>(Bv + x0);
        float4 c4 = *reinterpret_cast<const float4*>(C + x0);
        float al = A[xl], bl = Bv[xl], cl = C[xl];
        float ar = A[xr], br = Bv[xr], cr = C[xr];
        s[0] = fmaf(2.f, bl,   al)   + cl;   d[0] = cl   - al;
        s[1] = fmaf(2.f, b4.x, a4.x) + c4.x; d[1] = c4.x - a4.x;
        s[2] = fmaf(2.f, b4.y, a4.y) + c4.y; d[2] = c4.y - a4.y;
        s[3] = fmaf(2.f, b4.z, a4.z) + c4.z; d[3] = c4.z - a4.z;
        s[4] = fmaf(2.f, b4.w, a4.w) + c4.w; d[4] = c4.w - a4.w;
        s[5] = fmaf(2.f, br,   ar)   + cr;   d[5] = cr   - ar;
    }

    unsigned* h = &hist[(tid >> 4) * HSTRIDE];   // per-16-lane replica
    const float gwy = GW.g[y];
    const float4 gx4 = *reinterpret_cast<const float4*>(&GW.g[x0]);
    const float wv4[4] = {gwy * gx4.x, gwy * gx4.y, gwy * gx4.z, gwy * gx4.w};

    // front: gradients, magnitude, diamond-angle ratio u
    float U[4], MAG[4], XX[4], GY[4];
    #pragma unroll
    for (int i = 0; i < 4; ++i) {
        float gx8 = s[i + 2] - s[i];                          // 8*gx
        float gy8 = fmaf(2.f, d[i + 1], d[i]) + d[i + 2];     // 8*gy
        float m2  = fmaf(gx8, gx8, fmaf(gy8, gy8, 6.4e-7f));  // 64*(gx^2+gy^2+1e-8)
        MAG[i] = __builtin_amdgcn_sqrtf(m2) * wv4[i];         // ref_mag * 2^30
        float xx = gx8 + 8e-8f;                               // 8*(gx+1e-8)
        float ax = fabsf(xx), ay = fabsf(gy8);
        float den = (ax + ay) + 1e-37f;
        U[i]  = (ax - ay) * __builtin_amdgcn_rcpf(den);       // [-1,1]
        XX[i] = xx; GY[i] = gy8;
    }

    // packed poly: atan(u) in BIN units (deg-15 odd minimax, coeffs *36/2pi), two pairs
    f32x2 U01 = {U[0], U[1]}, U23 = {U[2], U[3]};
    f32x2 Z01 = pk_mul(U01, U01), Z23 = pk_mul(U23, U23);
    f32x2 P01 = pk_fma(CP(-2.32279295e-2f), Z01, CP(1.25257116e-1f));
    f32x2 P23 = pk_fma(CP(-2.32279295e-2f), Z23, CP(1.25257116e-1f));
    P01 = pk_fma(P01, Z01, CP(-3.20340049e-1f)); P23 = pk_fma(P23, Z23, CP(-3.20340049e-1f));
    P01 = pk_fma(P01, Z01, CP( 5.52446198e-1f)); P23 = pk_fma(P23, Z23, CP( 5.52446198e-1f));
    P01 = pk_fma(P01, Z01, CP(-7.96900272e-1f)); P23 = pk_fma(P23, Z23, CP(-7.96900272e-1f));
    P01 = pk_fma(P01, Z01, CP( 1.14285232f));    P23 = pk_fma(P23, Z23, CP( 1.14285232f));
    P01 = pk_fma(P01, Z01, CP(-1.90966007f));    P23 = pk_fma(P23, Z23, CP(-1.90966007f));
    P01 = pk_fma(P01, Z01, CP( 5.72957413f));    P23 = pk_fma(P23, Z23, CP( 5.72957413f));
    f32x2 PU01 = pk_mul(U01, P01), PU23 = pk_mul(U23, P23);
    const float pus[4] = {PU01.x, PU01.y, PU23.x, PU23.y};

    // tails: quadrant fold, bin split, fixed-point LDS atomics
    #pragma unroll
    for (int i = 0; i < 4; ++i) {
        float th = 4.5f - pus[i];                             // Q1 angle in bins [0,9]
        th = (XX[i] < 0.f) ? (18.f - th) : th;                // [0,18]
        unsigned sgn = __float_as_uint(GY[i]) & 0x80000000u;
        th = __uint_as_float(__float_as_uint(th) ^ sgn);      // [-18,18], sign of gy
        float ob  = fmaxf(th + 18.f, 0.f);                    // [0, 36+eps]
        int   ib  = (int)ob;                                  // trunc==floor; [0,36]
        float wo1 = __builtin_amdgcn_fractf(ob);
        float w1  = wo1 * MAG[i];
        float w0  = MAG[i] - w1;
        // bins 36,37 alias 0,1 — folded at reduce time (no per-pixel wrap)
        atomicAdd(&h[ib],     (unsigned)w0);
        atomicAdd(&h[ib + 1], (unsigned)w1);
    }
    __syncthreads();

    // ---- wave 0 only: fold aliases, exact u32 sums -> f64 (deterministic) ----
    if (tid < NBINS) {
        unsigned acc = 0;
        #pragma unroll
        for (int r = 0; r < HREP; ++r) acc += hist[r * HSTRIDE + tid];
        if (tid < 2) {
            #pragma unroll
            for (int r = 0; r < HREP; ++r) acc += hist[r * HSTRIDE + NBINS + tid];
        }
        binsd[tid] = (double)acc;
    }
    if (tid < NBINS) {
        int tm2 = tid - 2; if (tm2 < 0) tm2 += 36;
        int tm1 = tid - 1; if (tm1 < 0) tm1 += 36;
        int tp1 = tid + 1; if (tp1 >= 36) tp1 -= 36;
        int tp2 = tid + 2; if (tp2 >= 36) tp2 -= 36;
        smv[tid] = K2 * binsd[tm2] + K1 * binsd[tm1] + K0 * binsd[tid]
                 + K1 * binsd[tp1] + K2 * binsd[tp2];
    }
    if (tid < 64) {
        double v  = (tid < NBINS) ? smv[tid] : -1.0e300;
        int   idx = tid;
        #pragma unroll
        for (int o = 32; o >= 1; o >>= 1) {
            double ov = __shfl_xor(v, o);
            int    oi = __shfl_xor(idx, o);
            if (ov > v || (ov == v && oi < idx)) { v = ov; idx = oi; }
        }
        if (tid == 0) {
            int il = idx - 1; if (il < 0) il += 36;
            int ir = idx + 1; if (ir >= 36) ir -= 36;
            double l = smv[il], r = smv[ir];
            double c = 0.5 * (l - r) / (l + r - 2.0 * v);
            double ang = -(6.283185307179586 * ((double)idx + c) / 36.0 - 3.141592653589793);
            out[bid] = (float)ang;
        }
    }
}

extern "C" void kernel_launch(void* const* d_in, const int* in_sizes, int n_in,
                              void* d_out, int out_size, void* d_ws, size_t ws_size,
                              hipStream_t stream) {
    const float* patch = (const float*)d_in[0];
    float* out = (float*)d_out;
    const int B = in_sizes[0] >> 10;                     // 32768 patches
    patch_orient_kernel<<<B, 256, 0, stream>>>(patch, out);
}